// Round 3
// baseline (135.452 us; speedup 1.0000x reference)
//
#include <hip/hip_runtime.h>
#include <hip/hip_bf16.h>
#include <stdint.h>

typedef unsigned short u16;
typedef unsigned int   u32;
typedef __bf16  bf16x8 __attribute__((ext_vector_type(8)));
typedef float   f32x4  __attribute__((ext_vector_type(4)));

#define K_DIM  2048
#define N_E    16
#define HID    128
#define ODIM   64
#define NBATCH 8192

__device__ __forceinline__ u16 f2bf(float f) {
  u32 u = __builtin_bit_cast(u32, f);
  u32 r = (u + 0x7fffu + ((u >> 16) & 1u)) >> 16;   // RNE
  return (u16)r;
}
__device__ __forceinline__ float bf2f(u32 h) {
  return __builtin_bit_cast(float, h << 16);
}
__device__ __forceinline__ void gl_lds16(const void* g, void* l) {
  __builtin_amdgcn_global_load_lds(
      (const __attribute__((address_space(1))) u32*)g,
      (__attribute__((address_space(3))) u32*)l, 16, 0, 0);
}
__device__ __forceinline__ bf16x8 ld16(const void* p) {
  return __builtin_bit_cast(bf16x8, *(const uint4*)p);
}

// T3/T4 idiom (m201 template): RAW barrier (no waitcnt semantics) + targeted
// no-clobber waitcnts. "memory"-clobber asm would force vmcnt(0) drains at
// every barrier (the R2 mistake).
#define BAR()    __builtin_amdgcn_s_barrier()
#define LGKM0()  asm volatile("s_waitcnt lgkmcnt(0)")
#define WAITV6() asm volatile("s_waitcnt vmcnt(6)")
#define WAITV0() asm volatile("s_waitcnt vmcnt(0)")

// ---------------- prep: W1 [16][2048][128] f32 -> W1T [n=e*128+h][k] bf16 ----
__global__ __launch_bounds__(256) void k_prep_w1(const float* __restrict__ W1,
                                                 u16* __restrict__ W1T) {
  int gid = blockIdx.x * 256 + threadIdx.x;     // 524288 = 2048 n * 256 k8
  int n  = gid & 2047;
  int k8 = gid >> 11;
  const float* src = W1 + (size_t)(n >> 7) * (K_DIM * HID) + (n & 127);
  int kb = k8 * 8;
  u32 o0, o1, o2, o3;
  o0 = (u32)f2bf(src[(size_t)(kb+0)*HID]) | ((u32)f2bf(src[(size_t)(kb+1)*HID]) << 16);
  o1 = (u32)f2bf(src[(size_t)(kb+2)*HID]) | ((u32)f2bf(src[(size_t)(kb+3)*HID]) << 16);
  o2 = (u32)f2bf(src[(size_t)(kb+4)*HID]) | ((u32)f2bf(src[(size_t)(kb+5)*HID]) << 16);
  o3 = (u32)f2bf(src[(size_t)(kb+6)*HID]) | ((u32)f2bf(src[(size_t)(kb+7)*HID]) << 16);
  *(uint4*)(W1T + (size_t)n * K_DIM + kb) = make_uint4(o0, o1, o2, o3);
}

// ---------------- prep: W2 [16][128][64] f32 (== [r=2048][64]) -> W2T [o][r] bf16
__global__ __launch_bounds__(256) void k_prep_w2(const float* __restrict__ W2,
                                                 u16* __restrict__ W2T) {
  int gid = blockIdx.x * 256 + threadIdx.x;     // 16384 = 64 o * 256 r8
  int o  = gid & 63;
  int r8 = gid >> 6;
  int rb = r8 * 8;
  u32 o0, o1, o2, o3;
  o0 = (u32)f2bf(W2[(size_t)(rb+0)*64 + o]) | ((u32)f2bf(W2[(size_t)(rb+1)*64 + o]) << 16);
  o1 = (u32)f2bf(W2[(size_t)(rb+2)*64 + o]) | ((u32)f2bf(W2[(size_t)(rb+3)*64 + o]) << 16);
  o2 = (u32)f2bf(W2[(size_t)(rb+4)*64 + o]) | ((u32)f2bf(W2[(size_t)(rb+5)*64 + o]) << 16);
  o3 = (u32)f2bf(W2[(size_t)(rb+6)*64 + o]) | ((u32)f2bf(W2[(size_t)(rb+7)*64 + o]) << 16);
  *(uint4*)(W2T + (size_t)o * K_DIM + rb) = make_uint4(o0, o1, o2, o3);
}

// ---------------- prep: Wa [2048][16] f32 -> same layout bf16 -----------------
__global__ __launch_bounds__(256) void k_prep_wa(const float* __restrict__ Wa,
                                                 u16* __restrict__ WaB) {
  int gid = blockIdx.x * 256 + threadIdx.x;     // 4096 chunks of 8
  const float* s = Wa + (size_t)gid * 8;
  u32 o0 = (u32)f2bf(s[0]) | ((u32)f2bf(s[1]) << 16);
  u32 o1 = (u32)f2bf(s[2]) | ((u32)f2bf(s[3]) << 16);
  u32 o2 = (u32)f2bf(s[4]) | ((u32)f2bf(s[5]) << 16);
  u32 o3 = (u32)f2bf(s[6]) | ((u32)f2bf(s[7]) << 16);
  *(uint4*)(WaB + (size_t)gid * 8) = make_uint4(o0, o1, o2, o3);
}

// ---------------- fused: attn = softmax(z@Wa+ba), zb = bf16(z) ---------------
__global__ __launch_bounds__(256) void k_attn_cast(
    const float* __restrict__ z, const u16* __restrict__ WaB,
    const float* __restrict__ ba, u16* __restrict__ zb,
    float* __restrict__ attn) {
  __shared__ u16 waL[K_DIM * N_E];               // 64 KB
  int tid = threadIdx.x, l = tid & 63, w = tid >> 6;
#pragma unroll
  for (int c = 0; c < 16; ++c) {
    int off = (c * 4 + w) * 1024;                // bytes, wave-uniform dest
    gl_lds16((const char*)WaB + off + l * 16, (char*)waL + off);
  }
  __syncthreads();
  float bav[16];
#pragma unroll
  for (int e = 0; e < 16; ++e) bav[e] = ba[e];

  int rowbase = blockIdx.x * 32 + w * 8;
  for (int g = 0; g < 2; ++g) {
    int b = rowbase + g * 4;
    float acc[4][16] = {};
    for (int i = 0; i < 32; ++i) {
      int k = i * 64 + l;
      float zv[4];
#pragma unroll
      for (int j = 0; j < 4; ++j) {
        zv[j] = z[(size_t)(b + j) * K_DIM + k];
        zb[(size_t)(b + j) * K_DIM + k] = f2bf(zv[j]);
      }
      uint4 u0 = *(const uint4*)&waL[k * 16];
      uint4 u1 = *(const uint4*)&waL[k * 16 + 8];
      float wv[16];
      wv[0]  = bf2f(u0.x & 0xffffu); wv[1]  = bf2f(u0.x >> 16);
      wv[2]  = bf2f(u0.y & 0xffffu); wv[3]  = bf2f(u0.y >> 16);
      wv[4]  = bf2f(u0.z & 0xffffu); wv[5]  = bf2f(u0.z >> 16);
      wv[6]  = bf2f(u0.w & 0xffffu); wv[7]  = bf2f(u0.w >> 16);
      wv[8]  = bf2f(u1.x & 0xffffu); wv[9]  = bf2f(u1.x >> 16);
      wv[10] = bf2f(u1.y & 0xffffu); wv[11] = bf2f(u1.y >> 16);
      wv[12] = bf2f(u1.z & 0xffffu); wv[13] = bf2f(u1.z >> 16);
      wv[14] = bf2f(u1.w & 0xffffu); wv[15] = bf2f(u1.w >> 16);
#pragma unroll
      for (int j = 0; j < 4; ++j)
#pragma unroll
        for (int e = 0; e < 16; ++e)
          acc[j][e] = fmaf(zv[j], wv[e], acc[j][e]);
    }
#pragma unroll
    for (int s = 1; s < 64; s <<= 1)
#pragma unroll
      for (int j = 0; j < 4; ++j)
#pragma unroll
        for (int e = 0; e < 16; ++e)
          acc[j][e] += __shfl_xor(acc[j][e], s, 64);

#pragma unroll
    for (int j = 0; j < 4; ++j) {
      float p[16], m = -1e30f, ssum = 0.f;
#pragma unroll
      for (int e = 0; e < 16; ++e) { p[e] = acc[j][e] + bav[e]; m = fmaxf(m, p[e]); }
#pragma unroll
      for (int e = 0; e < 16; ++e) { p[e] = __expf(p[e] - m); ssum += p[e]; }
      float inv = 1.0f / ssum;
      float v = p[0] * inv;
#pragma unroll
      for (int e = 1; e < 16; ++e) { float pe = p[e] * inv; v = (l == e) ? pe : v; }
      if (l < 16) attn[(size_t)(b + j) * 16 + l] = v;
    }
  }
}

// ---------------- GEMM1: 256x256 8-phase (T2+T3+T4+T5) -----------------------
// h' = attn[e] * relu(zb @ W1T^T + b1), bf16 out.
// 8 waves (2M x 4N), BK=64, 128 KiB LDS: 2 buf x {A1,A2,B1,B2} 16KB regions.
#define RDA(BASE)                                                         \
  do {                                                                    \
    _Pragma("unroll")                                                     \
    for (int rf = 0; rf < 4; ++rf) {                                      \
      a[rf][0] = ld16((BASE) + aro + rf * 2048 + sw0);                    \
      a[rf][1] = ld16((BASE) + aro + rf * 2048 + sw1);                    \
    }                                                                     \
  } while (0)
#define RDB(BASE, BB)                                                     \
  do {                                                                    \
    _Pragma("unroll")                                                     \
    for (int cf = 0; cf < 2; ++cf) {                                      \
      BB[cf][0] = ld16((BASE) + bro + cf * 2048 + sw0);                   \
      BB[cf][1] = ld16((BASE) + bro + cf * 2048 + sw1);                   \
    }                                                                     \
  } while (0)
#define MM16(AA, BB, RO, CO)                                              \
  do {                                                                    \
    LGKM0();                                                              \
    __builtin_amdgcn_s_setprio(1);                                        \
    _Pragma("unroll")                                                     \
    for (int kh = 0; kh < 2; ++kh)                                        \
      _Pragma("unroll")                                                   \
      for (int rf = 0; rf < 4; ++rf)                                      \
        _Pragma("unroll")                                                 \
        for (int cf = 0; cf < 2; ++cf)                                    \
          acc[(RO) + rf][(CO) + cf] =                                     \
              __builtin_amdgcn_mfma_f32_16x16x32_bf16(                    \
                  AA[rf][kh], BB[cf][kh], acc[(RO) + rf][(CO) + cf],      \
                  0, 0, 0);                                               \
    __builtin_amdgcn_s_setprio(0);                                        \
  } while (0)

__global__ __launch_bounds__(512, 2) void k_gemm1(
    const u16* __restrict__ A, const u16* __restrict__ BT,
    const float* __restrict__ bias1, const float* __restrict__ attn,
    u16* __restrict__ H) {
  extern __shared__ char lds[];                  // 131072 B
  const int tid = threadIdx.x;
  const int l = tid & 63, w = tid >> 6;
  const int wm = w >> 2, wn = w & 3;
  const int rl = l & 15, kq = l >> 4;

  const int bid = blockIdx.x;
  const int swz = (bid & 7) * 32 + (bid >> 3);   // 256 % 8 == 0: bijective
  const int bm = swz >> 3, bn = swz & 7;
  const size_t brow = (size_t)bm * 256;
  const int bcol = bn * 256;

  // ---- staging source pointers (pre-swizzled global, linear LDS dest) ----
  const int slot = (tid & 7) ^ ((tid >> 3) & 7);
  const u16* sA0 = A + (brow + 0 * 128 + (tid >> 3)) * K_DIM + slot * 8;  // rows 0-63
  const u16* sA1 = A + (brow + 1 * 128 + (tid >> 3)) * K_DIM + slot * 8;  // rows 128-191
  const int bq0 = (tid >> 3) >> 5;
  const int bcr = (tid >> 3) & 31;
  const u16* sB0 = BT + (size_t)(bcol + (0 + bq0) * 64 + bcr) * K_DIM + slot * 8;
  const u16* sB1 = BT + (size_t)(bcol + (2 + bq0) * 64 + bcr) * K_DIM + slot * 8;

  char* const ldsw = lds + w * 1024;
  auto stA = [&](int p, int kt, int buf) {       // one 16KB part: 2 loads/thread
    char* d = ldsw + buf * 65536 + p * 16384;
    gl_lds16(sA0 + (size_t)p * (64 * K_DIM) + kt * 64, d);
    gl_lds16(sA1 + (size_t)p * (64 * K_DIM) + kt * 64, d + 8192);
  };
  auto stB = [&](int q, int kt, int buf) {
    char* d = ldsw + buf * 65536 + 32768 + q * 16384;
    gl_lds16(sB0 + (size_t)q * (32 * K_DIM) + kt * 64, d);
    gl_lds16(sB1 + (size_t)q * (32 * K_DIM) + kt * 64, d + 8192);
  };

  // ---- fragment read offsets (swizzled) ----
  const int sw0 = ((kq ^ (rl & 7)) << 4);        // kh=0: slot kq
  const int sw1 = (((4 + kq) ^ (rl & 7)) << 4);  // kh=1: slot 4+kq
  const int aro = (rl + wm * 64) * 128;
  const int bro = (wn * 32 + rl) * 128;

  f32x4  acc[8][4] = {};
  bf16x8 a[4][2], b0[2][2], b1r[2][2];

  // ---- prologue: stage 7 parts (tile0 complete, tile1 minus A2) ----
  stA(0, 0, 0); stB(0, 0, 0); stB(1, 0, 0); stA(1, 0, 0);
  stA(0, 1, 1); stB(0, 1, 1); stB(1, 1, 1);
  WAITV6(); BAR();

  const char* const L0 = lds;
  const char* const L1 = lds + 65536;
  // ---- main loop: 15 iters, tiles (t, t+1), stages (t+2, t+3) ----
  for (int t = 0; t < 30; t += 2) {
    // ph1: Q00(t)
    RDA(L0); RDB(L0 + 32768, b0);
    stA(1, t + 1, 1);
    BAR(); MM16(a, b0, 0, 0); BAR();
    // ph2: Q01(t)
    RDB(L0 + 49152, b1r);
    stA(0, t + 2, 0);
    BAR(); MM16(a, b1r, 0, 2); BAR();
    // ph3: Q10(t)
    RDA(L0 + 16384);
    stB(0, t + 2, 0);
    BAR(); MM16(a, b0, 4, 0); BAR();
    // ph4: Q11(t)
    stB(1, t + 2, 0);
    BAR(); MM16(a, b1r, 4, 2); WAITV6(); BAR();
    // ph5: Q00(t+1)
    RDA(L1); RDB(L1 + 32768, b0);
    stA(1, t + 2, 0);
    BAR(); MM16(a, b0, 0, 0); BAR();
    // ph6: Q01(t+1)
    RDB(L1 + 49152, b1r);
    stA(0, t + 3, 1);
    BAR(); MM16(a, b1r, 0, 2); BAR();
    // ph7: Q10(t+1)
    RDA(L1 + 16384);
    stB(0, t + 3, 1);
    BAR(); MM16(a, b0, 4, 0); BAR();
    // ph8: Q11(t+1)
    stB(1, t + 3, 1);
    BAR(); MM16(a, b1r, 4, 2); WAITV6(); BAR();
  }
  // ---- epilogue: tiles 30 (buf0), 31 (buf1) ----
  {
    RDA(L0); RDB(L0 + 32768, b0);
    stA(1, 31, 1);
    BAR(); MM16(a, b0, 0, 0); BAR();
    RDB(L0 + 49152, b1r);
    BAR(); MM16(a, b1r, 0, 2); BAR();
    RDA(L0 + 16384);
    BAR(); MM16(a, b0, 4, 0); BAR();
    BAR(); MM16(a, b1r, 4, 2); WAITV0(); BAR();
    RDA(L1); RDB(L1 + 32768, b0);
    BAR(); MM16(a, b0, 0, 0); BAR();
    RDB(L1 + 49152, b1r);
    BAR(); MM16(a, b1r, 0, 2); BAR();
    RDA(L1 + 16384);
    BAR(); MM16(a, b0, 4, 0); BAR();
    MM16(a, b1r, 4, 2);
  }

  // ---- C-write: bias + relu + attn scale -> bf16 H ----
  const int orow0 = kq * 4;
#pragma unroll
  for (int rf = 0; rf < 8; ++rf) {
    const size_t mbase = brow + wm * 128 + rf * 16 + orow0;
#pragma unroll
    for (int cf = 0; cf < 4; ++cf) {
      const int colT = wn * 64 + cf * 16 + rl;
      const int eg = bn * 2 + (colT >> 7);
      const float bias = bias1[eg * 128 + (colT & 127)];
#pragma unroll
      for (int i = 0; i < 4; ++i) {
        const size_t m = mbase + i;
        float v = acc[rf][cf][i] + bias;
        v = fmaxf(v, 0.f) * attn[m * 16 + eg];
        H[m * K_DIM + bcol + colT] = f2bf(v);
      }
    }
  }
}

// ---------------- GEMM2: out = h' @ W2T^T + (attn @ b2) ---------------------
__global__ __launch_bounds__(256) void k_gemm2(
    const u16* __restrict__ Hm, const u16* __restrict__ W2T,
    const float* __restrict__ attn, const float* __restrict__ b2,
    float* __restrict__ out) {
  __shared__ char lds2[2][12288];
  int tid = threadIdx.x, l = tid & 63, w = tid >> 6;
  int brow = blockIdx.x * 32;
  int srow = l >> 3, scol = (l & 7) * 8;
  auto stage = [&](int buf, int kt) {
    int k0 = kt * 64;
    gl_lds16(Hm + (size_t)(brow + w * 8 + srow) * K_DIM + k0 + scol,
             &lds2[buf][w * 1024]);
#pragma unroll
    for (int c = 0; c < 2; ++c) {
      int n = (c * 4 + w) * 8 + srow;
      gl_lds16(W2T + (size_t)n * K_DIM + k0 + scol,
               &lds2[buf][4096 + (c * 4 + w) * 1024]);
    }
  };
  f32x4 acc[2] = {};
  stage(0, 0);
  __syncthreads();
  int cur = 0;
  int rl = l & 15, kb = (l >> 4) * 16;
  for (int kt = 0; kt < 32; ++kt) {
    if (kt + 1 < 32) stage(cur ^ 1, kt + 1);
    const char* LA = lds2[cur];
    const char* LB = lds2[cur] + 4096;
#pragma unroll
    for (int kk = 0; kk < 2; ++kk) {
      bf16x8 bfr = ld16(LB + (w * 16 + rl) * 128 + kk * 64 + kb);
#pragma unroll
      for (int mi = 0; mi < 2; ++mi) {
        bf16x8 af = ld16(LA + (mi * 16 + rl) * 128 + kk * 64 + kb);
        acc[mi] = __builtin_amdgcn_mfma_f32_16x16x32_bf16(af, bfr, acc[mi], 0, 0, 0);
      }
    }
    __syncthreads();
    cur ^= 1;
  }
  int o = w * 16 + rl;
#pragma unroll
  for (int mi = 0; mi < 2; ++mi)
#pragma unroll
    for (int i = 0; i < 4; ++i) {
      int m = brow + mi * 16 + (l >> 4) * 4 + i;
      float v = acc[mi][i];
      const float* ar = attn + (size_t)m * 16;
#pragma unroll
      for (int e2 = 0; e2 < 16; ++e2) v = fmaf(ar[e2], b2[e2 * 64 + o], v);
      out[(size_t)m * 64 + o] = v;
    }
}

// ---------------- launch -----------------------------------------------------
extern "C" void kernel_launch(void* const* d_in, const int* in_sizes, int n_in,
                              void* d_out, int out_size, void* d_ws, size_t ws_size,
                              hipStream_t stream) {
  (void)in_sizes; (void)n_in; (void)out_size; (void)ws_size;
  const float* z  = (const float*)d_in[0];
  const float* W1 = (const float*)d_in[1];
  const float* b1 = (const float*)d_in[2];
  const float* W2 = (const float*)d_in[3];
  const float* b2 = (const float*)d_in[4];
  const float* Wa = (const float*)d_in[5];
  const float* ba = (const float*)d_in[6];
  float* out = (float*)d_out;
  char* ws = (char*)d_ws;
  u16*   W1T  = (u16*)(ws);                     // 8 MB
  u16*   W2T  = (u16*)(ws + 8388608);           // 256 KB
  u16*   WaB  = (u16*)(ws + 8650752);           // 64 KB
  u16*   zb   = (u16*)(ws + 8716288);           // 32 MB
  float* attn = (float*)(ws + 42270720);        // 512 KB
  u16*   H    = (u16*)(ws + 42795008);          // 32 MB

  (void)hipFuncSetAttribute((const void*)k_gemm1,
                            hipFuncAttributeMaxDynamicSharedMemorySize, 131072);

  k_prep_w1 <<<2048, 256, 0, stream>>>(W1, W1T);
  k_prep_w2 <<<64,   256, 0, stream>>>(W2, W2T);
  k_prep_wa <<<16,   256, 0, stream>>>(Wa, WaB);
  k_attn_cast<<<256, 256, 0, stream>>>(z, WaB, ba, zb, attn);
  k_gemm1   <<<256,  512, 131072, stream>>>(zb, W1T, b1, attn, H);
  k_gemm2   <<<256,  256, 0, stream>>>(H, W2T, attn, b2, out);
}

// Round 4
// 135.032 us; speedup vs baseline: 1.0031x; 1.0031x over previous
//
#include <hip/hip_runtime.h>
#include <hip/hip_bf16.h>
#include <stdint.h>

typedef unsigned short u16;
typedef unsigned int   u32;
typedef __bf16  bf16x8 __attribute__((ext_vector_type(8)));
typedef float   f32x4  __attribute__((ext_vector_type(4)));

#define K_DIM  2048
#define N_E    16
#define HID    128
#define ODIM   64
#define NBATCH 8192

__device__ __forceinline__ u16 f2bf(float f) {
  u32 u = __builtin_bit_cast(u32, f);
  u32 r = (u + 0x7fffu + ((u >> 16) & 1u)) >> 16;   // RNE
  return (u16)r;
}
__device__ __forceinline__ float bf2f(u32 h) {
  return __builtin_bit_cast(float, h << 16);
}
__device__ __forceinline__ void gl_lds16(const void* g, void* l) {
  __builtin_amdgcn_global_load_lds(
      (const __attribute__((address_space(1))) u32*)g,
      (__attribute__((address_space(3))) u32*)l, 16, 0, 0);
}
__device__ __forceinline__ bf16x8 ld16(const void* p) {
  return __builtin_bit_cast(bf16x8, *(const uint4*)p);
}

// T3/T4 idiom (m201 template): RAW barrier (no waitcnt semantics) + targeted
// no-clobber waitcnts. "memory"-clobber asm would force vmcnt(0) drains at
// every barrier (the R2 mistake).
#define BAR()    __builtin_amdgcn_s_barrier()
#define LGKM0()  asm volatile("s_waitcnt lgkmcnt(0)")
#define WAITV6() asm volatile("s_waitcnt vmcnt(6)")
#define WAITV0() asm volatile("s_waitcnt vmcnt(0)")

// ---------------- prep: W1 [16][2048][128] f32 -> W1T [n=e*128+h][k] bf16 ----
__global__ __launch_bounds__(256) void k_prep_w1(const float* __restrict__ W1,
                                                 u16* __restrict__ W1T) {
  int gid = blockIdx.x * 256 + threadIdx.x;     // 524288 = 2048 n * 256 k8
  int n  = gid & 2047;
  int k8 = gid >> 11;
  const float* src = W1 + (size_t)(n >> 7) * (K_DIM * HID) + (n & 127);
  int kb = k8 * 8;
  u32 o0, o1, o2, o3;
  o0 = (u32)f2bf(src[(size_t)(kb+0)*HID]) | ((u32)f2bf(src[(size_t)(kb+1)*HID]) << 16);
  o1 = (u32)f2bf(src[(size_t)(kb+2)*HID]) | ((u32)f2bf(src[(size_t)(kb+3)*HID]) << 16);
  o2 = (u32)f2bf(src[(size_t)(kb+4)*HID]) | ((u32)f2bf(src[(size_t)(kb+5)*HID]) << 16);
  o3 = (u32)f2bf(src[(size_t)(kb+6)*HID]) | ((u32)f2bf(src[(size_t)(kb+7)*HID]) << 16);
  *(uint4*)(W1T + (size_t)n * K_DIM + kb) = make_uint4(o0, o1, o2, o3);
}

// ---------------- prep: W2 [16][128][64] f32 (== [r=2048][64]) -> W2T [o][r] bf16
__global__ __launch_bounds__(256) void k_prep_w2(const float* __restrict__ W2,
                                                 u16* __restrict__ W2T) {
  int gid = blockIdx.x * 256 + threadIdx.x;     // 16384 = 64 o * 256 r8
  int o  = gid & 63;
  int r8 = gid >> 6;
  int rb = r8 * 8;
  u32 o0, o1, o2, o3;
  o0 = (u32)f2bf(W2[(size_t)(rb+0)*64 + o]) | ((u32)f2bf(W2[(size_t)(rb+1)*64 + o]) << 16);
  o1 = (u32)f2bf(W2[(size_t)(rb+2)*64 + o]) | ((u32)f2bf(W2[(size_t)(rb+3)*64 + o]) << 16);
  o2 = (u32)f2bf(W2[(size_t)(rb+4)*64 + o]) | ((u32)f2bf(W2[(size_t)(rb+5)*64 + o]) << 16);
  o3 = (u32)f2bf(W2[(size_t)(rb+6)*64 + o]) | ((u32)f2bf(W2[(size_t)(rb+7)*64 + o]) << 16);
  *(uint4*)(W2T + (size_t)o * K_DIM + rb) = make_uint4(o0, o1, o2, o3);
}

// ---------------- prep: Wa [2048][16] f32 -> same layout bf16 -----------------
__global__ __launch_bounds__(256) void k_prep_wa(const float* __restrict__ Wa,
                                                 u16* __restrict__ WaB) {
  int gid = blockIdx.x * 256 + threadIdx.x;     // 4096 chunks of 8
  const float* s = Wa + (size_t)gid * 8;
  u32 o0 = (u32)f2bf(s[0]) | ((u32)f2bf(s[1]) << 16);
  u32 o1 = (u32)f2bf(s[2]) | ((u32)f2bf(s[3]) << 16);
  u32 o2 = (u32)f2bf(s[4]) | ((u32)f2bf(s[5]) << 16);
  u32 o3 = (u32)f2bf(s[6]) | ((u32)f2bf(s[7]) << 16);
  *(uint4*)(WaB + (size_t)gid * 8) = make_uint4(o0, o1, o2, o3);
}

// ---------------- fused: attn = softmax(z@Wa+ba), zb = bf16(z) ---------------
__global__ __launch_bounds__(256) void k_attn_cast(
    const float* __restrict__ z, const u16* __restrict__ WaB,
    const float* __restrict__ ba, u16* __restrict__ zb,
    float* __restrict__ attn) {
  __shared__ u16 waL[K_DIM * N_E];               // 64 KB
  int tid = threadIdx.x, l = tid & 63, w = tid >> 6;
#pragma unroll
  for (int c = 0; c < 16; ++c) {
    int off = (c * 4 + w) * 1024;                // bytes, wave-uniform dest
    gl_lds16((const char*)WaB + off + l * 16, (char*)waL + off);
  }
  __syncthreads();
  float bav[16];
#pragma unroll
  for (int e = 0; e < 16; ++e) bav[e] = ba[e];

  int rowbase = blockIdx.x * 32 + w * 8;
  for (int g = 0; g < 2; ++g) {
    int b = rowbase + g * 4;
    float acc[4][16] = {};
    for (int i = 0; i < 32; ++i) {
      int k = i * 64 + l;
      float zv[4];
#pragma unroll
      for (int j = 0; j < 4; ++j) {
        zv[j] = z[(size_t)(b + j) * K_DIM + k];
        zb[(size_t)(b + j) * K_DIM + k] = f2bf(zv[j]);
      }
      uint4 u0 = *(const uint4*)&waL[k * 16];
      uint4 u1 = *(const uint4*)&waL[k * 16 + 8];
      float wv[16];
      wv[0]  = bf2f(u0.x & 0xffffu); wv[1]  = bf2f(u0.x >> 16);
      wv[2]  = bf2f(u0.y & 0xffffu); wv[3]  = bf2f(u0.y >> 16);
      wv[4]  = bf2f(u0.z & 0xffffu); wv[5]  = bf2f(u0.z >> 16);
      wv[6]  = bf2f(u0.w & 0xffffu); wv[7]  = bf2f(u0.w >> 16);
      wv[8]  = bf2f(u1.x & 0xffffu); wv[9]  = bf2f(u1.x >> 16);
      wv[10] = bf2f(u1.y & 0xffffu); wv[11] = bf2f(u1.y >> 16);
      wv[12] = bf2f(u1.z & 0xffffu); wv[13] = bf2f(u1.z >> 16);
      wv[14] = bf2f(u1.w & 0xffffu); wv[15] = bf2f(u1.w >> 16);
#pragma unroll
      for (int j = 0; j < 4; ++j)
#pragma unroll
        for (int e = 0; e < 16; ++e)
          acc[j][e] = fmaf(zv[j], wv[e], acc[j][e]);
    }
#pragma unroll
    for (int s = 1; s < 64; s <<= 1)
#pragma unroll
      for (int j = 0; j < 4; ++j)
#pragma unroll
        for (int e = 0; e < 16; ++e)
          acc[j][e] += __shfl_xor(acc[j][e], s, 64);

#pragma unroll
    for (int j = 0; j < 4; ++j) {
      float p[16], m = -1e30f, ssum = 0.f;
#pragma unroll
      for (int e = 0; e < 16; ++e) { p[e] = acc[j][e] + bav[e]; m = fmaxf(m, p[e]); }
#pragma unroll
      for (int e = 0; e < 16; ++e) { p[e] = __expf(p[e] - m); ssum += p[e]; }
      float inv = 1.0f / ssum;
      float v = p[0] * inv;
#pragma unroll
      for (int e = 1; e < 16; ++e) { float pe = p[e] * inv; v = (l == e) ? pe : v; }
      if (l < 16) attn[(size_t)(b + j) * 16 + l] = v;
    }
  }
}

// ---------------- GEMM1: 256x256 8-phase (T2+T3+T4+T5) -----------------------
// h' = attn[e] * relu(zb @ W1T^T + b1), bf16 out.
// 8 waves (2M x 4N), BK=64, 128 KiB LDS: 2 buf x {A1,A2,B1,B2} 16KB regions.
#define RDA(BASE)                                                         \
  do {                                                                    \
    _Pragma("unroll")                                                     \
    for (int rf = 0; rf < 4; ++rf) {                                      \
      a[rf][0] = ld16((BASE) + aro + rf * 2048 + sw0);                    \
      a[rf][1] = ld16((BASE) + aro + rf * 2048 + sw1);                    \
    }                                                                     \
  } while (0)
#define RDB(BASE, BB)                                                     \
  do {                                                                    \
    _Pragma("unroll")                                                     \
    for (int cf = 0; cf < 2; ++cf) {                                      \
      BB[cf][0] = ld16((BASE) + bro + cf * 2048 + sw0);                   \
      BB[cf][1] = ld16((BASE) + bro + cf * 2048 + sw1);                   \
    }                                                                     \
  } while (0)
#define MM16(AA, BB, RO, CO)                                              \
  do {                                                                    \
    LGKM0();                                                              \
    __builtin_amdgcn_s_setprio(1);                                        \
    _Pragma("unroll")                                                     \
    for (int kh = 0; kh < 2; ++kh)                                        \
      _Pragma("unroll")                                                   \
      for (int rf = 0; rf < 4; ++rf)                                      \
        _Pragma("unroll")                                                 \
        for (int cf = 0; cf < 2; ++cf)                                    \
          acc[(RO) + rf][(CO) + cf] =                                     \
              __builtin_amdgcn_mfma_f32_16x16x32_bf16(                    \
                  AA[rf][kh], BB[cf][kh], acc[(RO) + rf][(CO) + cf],      \
                  0, 0, 0);                                               \
    __builtin_amdgcn_s_setprio(0);                                        \
  } while (0)

__global__ __launch_bounds__(512, 2) void k_gemm1(
    const u16* __restrict__ A, const u16* __restrict__ BT,
    const float* __restrict__ bias1, const float* __restrict__ attn,
    u16* __restrict__ H) {
  extern __shared__ char lds[];                  // 131072 B
  const int tid = threadIdx.x;
  const int l = tid & 63, w = tid >> 6;
  const int wm = w >> 2, wn = w & 3;
  const int rl = l & 15, kq = l >> 4;

  const int bid = blockIdx.x;
  const int swz = (bid & 7) * 32 + (bid >> 3);   // 256 % 8 == 0: bijective
  const int bm = swz >> 3, bn = swz & 7;
  const size_t brow = (size_t)bm * 256;
  const int bcol = bn * 256;

  // ---- staging source pointers (pre-swizzled global, linear LDS dest) ----
  const int slot = (tid & 7) ^ ((tid >> 3) & 7);
  const u16* sA0 = A + (brow + 0 * 128 + (tid >> 3)) * K_DIM + slot * 8;  // rows 0-63
  const u16* sA1 = A + (brow + 1 * 128 + (tid >> 3)) * K_DIM + slot * 8;  // rows 128-191
  const int bq0 = (tid >> 3) >> 5;
  const int bcr = (tid >> 3) & 31;
  const u16* sB0 = BT + (size_t)(bcol + (0 + bq0) * 64 + bcr) * K_DIM + slot * 8;
  const u16* sB1 = BT + (size_t)(bcol + (2 + bq0) * 64 + bcr) * K_DIM + slot * 8;

  char* const ldsw = lds + w * 1024;
  auto stA = [&](int p, int kt, int buf) {       // one 16KB part: 2 loads/thread
    char* d = ldsw + buf * 65536 + p * 16384;
    gl_lds16(sA0 + (size_t)p * (64 * K_DIM) + kt * 64, d);
    gl_lds16(sA1 + (size_t)p * (64 * K_DIM) + kt * 64, d + 8192);
  };
  auto stB = [&](int q, int kt, int buf) {
    char* d = ldsw + buf * 65536 + 32768 + q * 16384;
    gl_lds16(sB0 + (size_t)q * (32 * K_DIM) + kt * 64, d);
    gl_lds16(sB1 + (size_t)q * (32 * K_DIM) + kt * 64, d + 8192);
  };

  // ---- fragment read offsets (swizzled) ----
  const int sw0 = ((kq ^ (rl & 7)) << 4);        // kh=0: slot kq
  const int sw1 = (((4 + kq) ^ (rl & 7)) << 4);  // kh=1: slot 4+kq
  const int aro = (rl + wm * 64) * 128;
  const int bro = (wn * 32 + rl) * 128;

  f32x4  acc[8][4] = {};
  bf16x8 a[4][2], b0[2][2], b1r[2][2];

  // ---- prologue: stage 7 parts (tile0 complete, tile1 minus A2) ----
  stA(0, 0, 0); stB(0, 0, 0); stB(1, 0, 0); stA(1, 0, 0);
  stA(0, 1, 1); stB(0, 1, 1); stB(1, 1, 1);
  WAITV6(); BAR();

  const char* const L0 = lds;
  const char* const L1 = lds + 65536;
  // ---- main loop: 15 iters, tiles (t, t+1), stages (t+2, t+3) ----
  for (int t = 0; t < 30; t += 2) {
    // ph1: Q00(t)
    RDA(L0); RDB(L0 + 32768, b0);
    stA(1, t + 1, 1);
    BAR(); MM16(a, b0, 0, 0); BAR();
    // ph2: Q01(t)
    RDB(L0 + 49152, b1r);
    stA(0, t + 2, 0);
    BAR(); MM16(a, b1r, 0, 2); BAR();
    // ph3: Q10(t)
    RDA(L0 + 16384);
    stB(0, t + 2, 0);
    BAR(); MM16(a, b0, 4, 0); BAR();
    // ph4: Q11(t)
    stB(1, t + 2, 0);
    BAR(); MM16(a, b1r, 4, 2); WAITV6(); BAR();
    // ph5: Q00(t+1)
    RDA(L1); RDB(L1 + 32768, b0);
    stA(1, t + 2, 0);
    BAR(); MM16(a, b0, 0, 0); BAR();
    // ph6: Q01(t+1)
    RDB(L1 + 49152, b1r);
    stA(0, t + 3, 1);
    BAR(); MM16(a, b1r, 0, 2); BAR();
    // ph7: Q10(t+1)
    RDA(L1 + 16384);
    stB(0, t + 3, 1);
    BAR(); MM16(a, b0, 4, 0); BAR();
    // ph8: Q11(t+1)
    stB(1, t + 3, 1);
    BAR(); MM16(a, b1r, 4, 2); WAITV6(); BAR();
  }
  // ---- epilogue: tiles 30 (buf0), 31 (buf1) ----
  {
    RDA(L0); RDB(L0 + 32768, b0);
    stA(1, 31, 1);
    BAR(); MM16(a, b0, 0, 0); BAR();
    RDB(L0 + 49152, b1r);
    BAR(); MM16(a, b1r, 0, 2); BAR();
    RDA(L0 + 16384);
    BAR(); MM16(a, b0, 4, 0); BAR();
    BAR(); MM16(a, b1r, 4, 2); WAITV0(); BAR();
    RDA(L1); RDB(L1 + 32768, b0);
    BAR(); MM16(a, b0, 0, 0); BAR();
    RDB(L1 + 49152, b1r);
    BAR(); MM16(a, b1r, 0, 2); BAR();
    RDA(L1 + 16384);
    BAR(); MM16(a, b0, 4, 0); BAR();
    MM16(a, b1r, 4, 2);
  }

  // ---- C-write: bias + relu + attn scale -> bf16 H ----
  const int orow0 = kq * 4;
#pragma unroll
  for (int rf = 0; rf < 8; ++rf) {
    const size_t mbase = brow + wm * 128 + rf * 16 + orow0;
#pragma unroll
    for (int cf = 0; cf < 4; ++cf) {
      const int colT = wn * 64 + cf * 16 + rl;
      const int eg = bn * 2 + (colT >> 7);
      const float bias = bias1[eg * 128 + (colT & 127)];
#pragma unroll
      for (int i = 0; i < 4; ++i) {
        const size_t m = mbase + i;
        float v = acc[rf][cf][i] + bias;
        v = fmaxf(v, 0.f) * attn[m * 16 + eg];
        H[m * K_DIM + bcol + colT] = f2bf(v);
      }
    }
  }
}

// ---------------- GEMM2: out = h' @ W2T^T + (attn @ b2) ---------------------
__global__ __launch_bounds__(256) void k_gemm2(
    const u16* __restrict__ Hm, const u16* __restrict__ W2T,
    const float* __restrict__ attn, const float* __restrict__ b2,
    float* __restrict__ out) {
  __shared__ char lds2[2][12288];
  int tid = threadIdx.x, l = tid & 63, w = tid >> 6;
  int brow = blockIdx.x * 32;
  int srow = l >> 3, scol = (l & 7) * 8;
  auto stage = [&](int buf, int kt) {
    int k0 = kt * 64;
    gl_lds16(Hm + (size_t)(brow + w * 8 + srow) * K_DIM + k0 + scol,
             &lds2[buf][w * 1024]);
#pragma unroll
    for (int c = 0; c < 2; ++c) {
      int n = (c * 4 + w) * 8 + srow;
      gl_lds16(W2T + (size_t)n * K_DIM + k0 + scol,
               &lds2[buf][4096 + (c * 4 + w) * 1024]);
    }
  };
  f32x4 acc[2] = {};
  stage(0, 0);
  __syncthreads();
  int cur = 0;
  int rl = l & 15, kb = (l >> 4) * 16;
  for (int kt = 0; kt < 32; ++kt) {
    if (kt + 1 < 32) stage(cur ^ 1, kt + 1);
    const char* LA = lds2[cur];
    const char* LB = lds2[cur] + 4096;
#pragma unroll
    for (int kk = 0; kk < 2; ++kk) {
      bf16x8 bfr = ld16(LB + (w * 16 + rl) * 128 + kk * 64 + kb);
#pragma unroll
      for (int mi = 0; mi < 2; ++mi) {
        bf16x8 af = ld16(LA + (mi * 16 + rl) * 128 + kk * 64 + kb);
        acc[mi] = __builtin_amdgcn_mfma_f32_16x16x32_bf16(af, bfr, acc[mi], 0, 0, 0);
      }
    }
    __syncthreads();
    cur ^= 1;
  }
  int o = w * 16 + rl;
#pragma unroll
  for (int mi = 0; mi < 2; ++mi)
#pragma unroll
    for (int i = 0; i < 4; ++i) {
      int m = brow + mi * 16 + (l >> 4) * 4 + i;
      float v = acc[mi][i];
      const float* ar = attn + (size_t)m * 16;
#pragma unroll
      for (int e2 = 0; e2 < 16; ++e2) v = fmaf(ar[e2], b2[e2 * 64 + o], v);
      out[(size_t)m * 64 + o] = v;
    }
}

// ---------------- launch -----------------------------------------------------
extern "C" void kernel_launch(void* const* d_in, const int* in_sizes, int n_in,
                              void* d_out, int out_size, void* d_ws, size_t ws_size,
                              hipStream_t stream) {
  (void)in_sizes; (void)n_in; (void)out_size; (void)ws_size;
  const float* z  = (const float*)d_in[0];
  const float* W1 = (const float*)d_in[1];
  const float* b1 = (const float*)d_in[2];
  const float* W2 = (const float*)d_in[3];
  const float* b2 = (const float*)d_in[4];
  const float* Wa = (const float*)d_in[5];
  const float* ba = (const float*)d_in[6];
  float* out = (float*)d_out;
  char* ws = (char*)d_ws;
  u16*   W1T  = (u16*)(ws);                     // 8 MB
  u16*   W2T  = (u16*)(ws + 8388608);           // 256 KB
  u16*   WaB  = (u16*)(ws + 8650752);           // 64 KB
  u16*   zb   = (u16*)(ws + 8716288);           // 32 MB
  float* attn = (float*)(ws + 42270720);        // 512 KB
  u16*   H    = (u16*)(ws + 42795008);          // 32 MB

  (void)hipFuncSetAttribute((const void*)k_gemm1,
                            hipFuncAttributeMaxDynamicSharedMemorySize, 131072);

  k_prep_w1 <<<2048, 256, 0, stream>>>(W1, W1T);
  k_prep_w2 <<<64,   256, 0, stream>>>(W2, W2T);
  k_prep_wa <<<16,   256, 0, stream>>>(Wa, WaB);
  k_attn_cast<<<256, 256, 0, stream>>>(z, WaB, ba, zb, attn);
  k_gemm1   <<<256,  512, 131072, stream>>>(zb, W1T, b1, attn, H);
  k_gemm2   <<<256,  256, 0, stream>>>(H, W2T, attn, b2, out);
}

// Round 5
// 133.253 us; speedup vs baseline: 1.0165x; 1.0133x over previous
//
#include <hip/hip_runtime.h>
#include <hip/hip_bf16.h>
#include <stdint.h>

typedef unsigned short u16;
typedef unsigned int   u32;
typedef __bf16  bf16x8 __attribute__((ext_vector_type(8)));
typedef float   f32x4  __attribute__((ext_vector_type(4)));

#define K_DIM  2048
#define N_E    16
#define HID    128
#define ODIM   64
#define NBATCH 8192

__device__ __forceinline__ u16 f2bf(float f) {
  u32 u = __builtin_bit_cast(u32, f);
  u32 r = (u + 0x7fffu + ((u >> 16) & 1u)) >> 16;   // RNE
  return (u16)r;
}
__device__ __forceinline__ float bf2f(u32 h) {
  return __builtin_bit_cast(float, h << 16);
}
__device__ __forceinline__ void gl_lds16(const void* g, void* l) {
  __builtin_amdgcn_global_load_lds(
      (const __attribute__((address_space(1))) u32*)g,
      (__attribute__((address_space(3))) u32*)l, 16, 0, 0);
}
__device__ __forceinline__ bf16x8 ld16(const void* p) {
  return __builtin_bit_cast(bf16x8, *(const uint4*)p);
}

#define BAR()     __builtin_amdgcn_s_barrier()
#define LGKM0()   asm volatile("s_waitcnt lgkmcnt(0)")
#define LGKM8()   asm volatile("s_waitcnt lgkmcnt(8)")
#define WAITV6()  asm volatile("s_waitcnt vmcnt(6)")
#define WAITV8()  asm volatile("s_waitcnt vmcnt(8)")
#define WAITV10() asm volatile("s_waitcnt vmcnt(10)")
#define WAITV0()  asm volatile("s_waitcnt vmcnt(0)")

// ---------------- prep: W1 [16][2048][128] f32 -> W1T [n=e*128+h][k] bf16 ----
__global__ __launch_bounds__(256) void k_prep_w1(const float* __restrict__ W1,
                                                 u16* __restrict__ W1T) {
  int gid = blockIdx.x * 256 + threadIdx.x;     // 524288 = 2048 n * 256 k8
  int n  = gid & 2047;
  int k8 = gid >> 11;
  const float* src = W1 + (size_t)(n >> 7) * (K_DIM * HID) + (n & 127);
  int kb = k8 * 8;
  u32 o0, o1, o2, o3;
  o0 = (u32)f2bf(src[(size_t)(kb+0)*HID]) | ((u32)f2bf(src[(size_t)(kb+1)*HID]) << 16);
  o1 = (u32)f2bf(src[(size_t)(kb+2)*HID]) | ((u32)f2bf(src[(size_t)(kb+3)*HID]) << 16);
  o2 = (u32)f2bf(src[(size_t)(kb+4)*HID]) | ((u32)f2bf(src[(size_t)(kb+5)*HID]) << 16);
  o3 = (u32)f2bf(src[(size_t)(kb+6)*HID]) | ((u32)f2bf(src[(size_t)(kb+7)*HID]) << 16);
  *(uint4*)(W1T + (size_t)n * K_DIM + kb) = make_uint4(o0, o1, o2, o3);
}

// ---------------- prep: W2 [16][128][64] f32 (== [r=2048][64]) -> W2T [o][r] bf16
__global__ __launch_bounds__(256) void k_prep_w2(const float* __restrict__ W2,
                                                 u16* __restrict__ W2T) {
  int gid = blockIdx.x * 256 + threadIdx.x;     // 16384 = 64 o * 256 r8
  int o  = gid & 63;
  int r8 = gid >> 6;
  int rb = r8 * 8;
  u32 o0, o1, o2, o3;
  o0 = (u32)f2bf(W2[(size_t)(rb+0)*64 + o]) | ((u32)f2bf(W2[(size_t)(rb+1)*64 + o]) << 16);
  o1 = (u32)f2bf(W2[(size_t)(rb+2)*64 + o]) | ((u32)f2bf(W2[(size_t)(rb+3)*64 + o]) << 16);
  o2 = (u32)f2bf(W2[(size_t)(rb+4)*64 + o]) | ((u32)f2bf(W2[(size_t)(rb+5)*64 + o]) << 16);
  o3 = (u32)f2bf(W2[(size_t)(rb+6)*64 + o]) | ((u32)f2bf(W2[(size_t)(rb+7)*64 + o]) << 16);
  *(uint4*)(W2T + (size_t)o * K_DIM + rb) = make_uint4(o0, o1, o2, o3);
}

// ---------------- prep: Wa [2048][16] f32 -> same layout bf16 -----------------
__global__ __launch_bounds__(256) void k_prep_wa(const float* __restrict__ Wa,
                                                 u16* __restrict__ WaB) {
  int gid = blockIdx.x * 256 + threadIdx.x;     // 4096 chunks of 8
  const float* s = Wa + (size_t)gid * 8;
  u32 o0 = (u32)f2bf(s[0]) | ((u32)f2bf(s[1]) << 16);
  u32 o1 = (u32)f2bf(s[2]) | ((u32)f2bf(s[3]) << 16);
  u32 o2 = (u32)f2bf(s[4]) | ((u32)f2bf(s[5]) << 16);
  u32 o3 = (u32)f2bf(s[6]) | ((u32)f2bf(s[7]) << 16);
  *(uint4*)(WaB + (size_t)gid * 8) = make_uint4(o0, o1, o2, o3);
}

// ---------------- fused: attn = softmax(z@Wa+ba), zb = bf16(z) ---------------
// v2: no LDS (Wa reads hit L2, fully coalesced), 1024 blocks x 4 waves,
// 2 rows per wave, lane owns 4 consecutive k -> float4 z loads, uint2 zb stores.
__global__ __launch_bounds__(256) void k_attn_cast(
    const float* __restrict__ z, const u16* __restrict__ WaB,
    const float* __restrict__ ba, u16* __restrict__ zb,
    float* __restrict__ attn) {
  const int tid = threadIdx.x, l = tid & 63, w = tid >> 6;
  const int r0 = blockIdx.x * 8 + w * 2;         // rows r0, r0+1
  const float* z0p = z + (size_t)r0 * K_DIM;
  const float* z1p = z0p + K_DIM;
  u16* zb0 = zb + (size_t)r0 * K_DIM;
  u16* zb1 = zb0 + K_DIM;

  float bav[16];
#pragma unroll
  for (int e = 0; e < 16; ++e) bav[e] = ba[e];

  float acc0[16] = {}, acc1[16] = {};
#pragma unroll
  for (int i = 0; i < 8; ++i) {
    const int kb = i * 256 + l * 4;              // 4 consecutive k per lane
    float4 za = *(const float4*)(z0p + kb);
    float4 zc = *(const float4*)(z1p + kb);
    const float zr0[4] = {za.x, za.y, za.z, za.w};
    const float zr1[4] = {zc.x, zc.y, zc.z, zc.w};
#pragma unroll
    for (int kk = 0; kk < 4; ++kk) {
      const uint4* wp = (const uint4*)(WaB + (size_t)(kb + kk) * 16);
      uint4 u0 = wp[0], u1 = wp[1];
      float wv[16];
      wv[0]  = bf2f(u0.x & 0xffffu); wv[1]  = bf2f(u0.x >> 16);
      wv[2]  = bf2f(u0.y & 0xffffu); wv[3]  = bf2f(u0.y >> 16);
      wv[4]  = bf2f(u0.z & 0xffffu); wv[5]  = bf2f(u0.z >> 16);
      wv[6]  = bf2f(u0.w & 0xffffu); wv[7]  = bf2f(u0.w >> 16);
      wv[8]  = bf2f(u1.x & 0xffffu); wv[9]  = bf2f(u1.x >> 16);
      wv[10] = bf2f(u1.y & 0xffffu); wv[11] = bf2f(u1.y >> 16);
      wv[12] = bf2f(u1.z & 0xffffu); wv[13] = bf2f(u1.z >> 16);
      wv[14] = bf2f(u1.w & 0xffffu); wv[15] = bf2f(u1.w >> 16);
#pragma unroll
      for (int e = 0; e < 16; ++e) {
        acc0[e] = fmaf(zr0[kk], wv[e], acc0[e]);
        acc1[e] = fmaf(zr1[kk], wv[e], acc1[e]);
      }
    }
    // cast + store zb (8B per row per lane, coalesced)
    uint2 p0, p1;
    p0.x = (u32)f2bf(zr0[0]) | ((u32)f2bf(zr0[1]) << 16);
    p0.y = (u32)f2bf(zr0[2]) | ((u32)f2bf(zr0[3]) << 16);
    p1.x = (u32)f2bf(zr1[0]) | ((u32)f2bf(zr1[1]) << 16);
    p1.y = (u32)f2bf(zr1[2]) | ((u32)f2bf(zr1[3]) << 16);
    *(uint2*)(zb0 + kb) = p0;
    *(uint2*)(zb1 + kb) = p1;
  }

  // butterfly reduce across 64 lanes (each lane ends with full sums)
#pragma unroll
  for (int s = 1; s < 64; s <<= 1)
#pragma unroll
    for (int e = 0; e < 16; ++e) {
      acc0[e] += __shfl_xor(acc0[e], s, 64);
      acc1[e] += __shfl_xor(acc1[e], s, 64);
    }

  // softmax (redundant across lanes), lane<16 writes
  {
    float p[16], m = -1e30f, ssum = 0.f;
#pragma unroll
    for (int e = 0; e < 16; ++e) { p[e] = acc0[e] + bav[e]; m = fmaxf(m, p[e]); }
#pragma unroll
    for (int e = 0; e < 16; ++e) { p[e] = __expf(p[e] - m); ssum += p[e]; }
    float inv = 1.0f / ssum;
    float v = p[0] * inv;
#pragma unroll
    for (int e = 1; e < 16; ++e) { float pe = p[e] * inv; v = (l == e) ? pe : v; }
    if (l < 16) attn[(size_t)r0 * 16 + l] = v;
  }
  {
    float p[16], m = -1e30f, ssum = 0.f;
#pragma unroll
    for (int e = 0; e < 16; ++e) { p[e] = acc1[e] + bav[e]; m = fmaxf(m, p[e]); }
#pragma unroll
    for (int e = 0; e < 16; ++e) { p[e] = __expf(p[e] - m); ssum += p[e]; }
    float inv = 1.0f / ssum;
    float v = p[0] * inv;
#pragma unroll
    for (int e = 1; e < 16; ++e) { float pe = p[e] * inv; v = (l == e) ? pe : v; }
    if (l < 16) attn[(size_t)(r0 + 1) * 16 + l] = v;
  }
}

// ---------------- GEMM1: 256x256 8-phase (T2+T3+T4+T5) -----------------------
// h' = attn[e] * relu(zb @ W1T^T + b1), bf16 out.
// 8 waves (2M x 4N), BK=64, 128 KiB LDS: 2 buf x {A1,A2,B1,B2} 16KB regions.
#define RDA(BASE)                                                         \
  do {                                                                    \
    _Pragma("unroll")                                                     \
    for (int rf = 0; rf < 4; ++rf) {                                      \
      a[rf][0] = ld16((BASE) + aro + rf * 2048 + sw0);                    \
      a[rf][1] = ld16((BASE) + aro + rf * 2048 + sw1);                    \
    }                                                                     \
  } while (0)
#define RDB(BASE, BB)                                                     \
  do {                                                                    \
    _Pragma("unroll")                                                     \
    for (int cf = 0; cf < 2; ++cf) {                                      \
      BB[cf][0] = ld16((BASE) + bro + cf * 2048 + sw0);                   \
      BB[cf][1] = ld16((BASE) + bro + cf * 2048 + sw1);                   \
    }                                                                     \
  } while (0)
#define MM16(AA, BB, RO, CO)                                              \
  do {                                                                    \
    LGKM0();                                                              \
    __builtin_amdgcn_s_setprio(1);                                        \
    _Pragma("unroll")                                                     \
    for (int kh = 0; kh < 2; ++kh)                                        \
      _Pragma("unroll")                                                   \
      for (int rf = 0; rf < 4; ++rf)                                      \
        _Pragma("unroll")                                                 \
        for (int cf = 0; cf < 2; ++cf)                                    \
          acc[(RO) + rf][(CO) + cf] =                                     \
              __builtin_amdgcn_mfma_f32_16x16x32_bf16(                    \
                  AA[rf][kh], BB[cf][kh], acc[(RO) + rf][(CO) + cf],      \
                  0, 0, 0);                                               \
    __builtin_amdgcn_s_setprio(0);                                        \
  } while (0)

__global__ __launch_bounds__(512, 2) void k_gemm1(
    const u16* __restrict__ A, const u16* __restrict__ BT,
    const float* __restrict__ bias1, const float* __restrict__ attn,
    u16* __restrict__ H) {
  extern __shared__ char lds[];                  // 131072 B
  const int tid = threadIdx.x;
  const int l = tid & 63, w = tid >> 6;
  const int wm = w >> 2, wn = w & 3;
  const int rl = l & 15, kq = l >> 4;

  const int bid = blockIdx.x;
  const int swz = (bid & 7) * 32 + (bid >> 3);   // 256 % 8 == 0: bijective
  const int bm = swz >> 3, bn = swz & 7;
  const size_t brow = (size_t)bm * 256;
  const int bcol = bn * 256;

  // ---- staging source pointers (pre-swizzled global, linear LDS dest) ----
  const int slot = (tid & 7) ^ ((tid >> 3) & 7);
  const u16* sA0 = A + (brow + 0 * 128 + (tid >> 3)) * K_DIM + slot * 8;  // rows 0-63
  const u16* sA1 = A + (brow + 1 * 128 + (tid >> 3)) * K_DIM + slot * 8;  // rows 128-191
  const int bq0 = (tid >> 3) >> 5;
  const int bcr = (tid >> 3) & 31;
  const u16* sB0 = BT + (size_t)(bcol + (0 + bq0) * 64 + bcr) * K_DIM + slot * 8;
  const u16* sB1 = BT + (size_t)(bcol + (2 + bq0) * 64 + bcr) * K_DIM + slot * 8;

  char* const ldsw = lds + w * 1024;
  auto stA = [&](int p, int kt, int buf) {       // one 16KB part: 2 loads/thread
    char* d = ldsw + buf * 65536 + p * 16384;
    gl_lds16(sA0 + (size_t)p * (64 * K_DIM) + kt * 64, d);
    gl_lds16(sA1 + (size_t)p * (64 * K_DIM) + kt * 64, d + 8192);
  };
  auto stB = [&](int q, int kt, int buf) {
    char* d = ldsw + buf * 65536 + 32768 + q * 16384;
    gl_lds16(sB0 + (size_t)q * (32 * K_DIM) + kt * 64, d);
    gl_lds16(sB1 + (size_t)q * (32 * K_DIM) + kt * 64, d + 8192);
  };

  // ---- fragment read offsets (swizzled) ----
  const int sw0 = ((kq ^ (rl & 7)) << 4);        // kh=0: slot kq
  const int sw1 = (((4 + kq) ^ (rl & 7)) << 4);  // kh=1: slot 4+kq
  const int aro = (rl + wm * 64) * 128;
  const int bro = (wn * 32 + rl) * 128;

  f32x4  acc[8][4] = {};
  bf16x8 a[4][2], b0[2][2], b1r[2][2];

  // ---- prologue: stage 7 parts (tile0 complete, tile1 minus A2) ----
  stA(0, 0, 0); stB(0, 0, 0); stB(1, 0, 0); stA(1, 0, 0);
  stA(0, 1, 1); stB(0, 1, 1); stB(1, 1, 1);
  WAITV6(); BAR();

  const char* const L0 = lds;
  const char* const L1 = lds + 65536;
  // ---- main loop: 15 iters, tiles (t, t+1), stages (t+2, t+3) ----
  for (int t = 0; t < 30; t += 2) {
    // ph1: Q00(t)
    RDA(L0); RDB(L0 + 32768, b0);
    stA(1, t + 1, 1);
    LGKM8();
    BAR(); MM16(a, b0, 0, 0); BAR();
    // ph2: Q01(t)
    RDB(L0 + 49152, b1r);
    stA(0, t + 2, 0);
    BAR(); MM16(a, b1r, 0, 2); BAR();
    // ph3: Q10(t)
    RDA(L0 + 16384);
    stB(0, t + 2, 0);
    BAR(); MM16(a, b0, 4, 0); BAR();
    // ph4: Q11(t)  — relaxed wait: only needs buf1-tile(t+1) A1/B1/B2
    //              (staged >= prev-iter ph6); newest 8 = ph1..ph4 stages.
    stB(1, t + 2, 0);
    BAR(); MM16(a, b1r, 4, 2); WAITV8(); BAR();
    // ph5: Q00(t+1)
    RDA(L1); RDB(L1 + 32768, b0);
    stA(1, t + 2, 0);
    LGKM8();
    BAR(); MM16(a, b0, 0, 0); BAR();
    // ph6: Q01(t+1)  — vmcnt(10) covers ph1's stA(1,t+1,1) before ph7 reads it
    RDB(L1 + 49152, b1r);
    stA(0, t + 3, 1);
    BAR(); MM16(a, b1r, 0, 2); WAITV10(); BAR();
    // ph7: Q10(t+1)
    RDA(L1 + 16384);
    stB(0, t + 3, 1);
    BAR(); MM16(a, b0, 4, 0); BAR();
    // ph8: Q11(t+1)  — vmcnt(6): covers buf0-tile(t+2) parts (ph2..ph5)
    stB(1, t + 3, 1);
    BAR(); MM16(a, b1r, 4, 2); WAITV6(); BAR();
  }
  // ---- epilogue: tiles 30 (buf0), 31 (buf1) ----
  {
    RDA(L0); RDB(L0 + 32768, b0);
    stA(1, 31, 1);
    LGKM8();
    BAR(); MM16(a, b0, 0, 0); BAR();
    RDB(L0 + 49152, b1r);
    BAR(); MM16(a, b1r, 0, 2); BAR();
    RDA(L0 + 16384);
    BAR(); MM16(a, b0, 4, 0); BAR();
    BAR(); MM16(a, b1r, 4, 2); WAITV0(); BAR();
    RDA(L1); RDB(L1 + 32768, b0);
    BAR(); MM16(a, b0, 0, 0); BAR();
    RDB(L1 + 49152, b1r);
    BAR(); MM16(a, b1r, 0, 2); BAR();
    RDA(L1 + 16384);
    BAR(); MM16(a, b0, 4, 0); BAR();
    MM16(a, b1r, 4, 2);
  }

  // ---- C-write: bias + relu + attn scale -> bf16 H ----
  const int orow0 = kq * 4;
#pragma unroll
  for (int rf = 0; rf < 8; ++rf) {
    const size_t mbase = brow + wm * 128 + rf * 16 + orow0;
#pragma unroll
    for (int cf = 0; cf < 4; ++cf) {
      const int colT = wn * 64 + cf * 16 + rl;
      const int eg = bn * 2 + (colT >> 7);
      const float bias = bias1[eg * 128 + (colT & 127)];
#pragma unroll
      for (int i = 0; i < 4; ++i) {
        const size_t m = mbase + i;
        float v = acc[rf][cf][i] + bias;
        v = fmaxf(v, 0.f) * attn[m * 16 + eg];
        H[m * K_DIM + bcol + colT] = f2bf(v);
      }
    }
  }
}

// ---------------- GEMM2: out = h' @ W2T^T + (attn @ b2) ---------------------
__global__ __launch_bounds__(256) void k_gemm2(
    const u16* __restrict__ Hm, const u16* __restrict__ W2T,
    const float* __restrict__ attn, const float* __restrict__ b2,
    float* __restrict__ out) {
  __shared__ char lds2[2][12288];
  int tid = threadIdx.x, l = tid & 63, w = tid >> 6;
  int brow = blockIdx.x * 32;
  int srow = l >> 3, scol = (l & 7) * 8;
  auto stage = [&](int buf, int kt) {
    int k0 = kt * 64;
    gl_lds16(Hm + (size_t)(brow + w * 8 + srow) * K_DIM + k0 + scol,
             &lds2[buf][w * 1024]);
#pragma unroll
    for (int c = 0; c < 2; ++c) {
      int n = (c * 4 + w) * 8 + srow;
      gl_lds16(W2T + (size_t)n * K_DIM + k0 + scol,
               &lds2[buf][4096 + (c * 4 + w) * 1024]);
    }
  };
  f32x4 acc[2] = {};
  stage(0, 0);
  __syncthreads();
  int cur = 0;
  int rl = l & 15, kb = (l >> 4) * 16;
  for (int kt = 0; kt < 32; ++kt) {
    if (kt + 1 < 32) stage(cur ^ 1, kt + 1);
    const char* LA = lds2[cur];
    const char* LB = lds2[cur] + 4096;
#pragma unroll
    for (int kk = 0; kk < 2; ++kk) {
      bf16x8 bfr = ld16(LB + (w * 16 + rl) * 128 + kk * 64 + kb);
#pragma unroll
      for (int mi = 0; mi < 2; ++mi) {
        bf16x8 af = ld16(LA + (mi * 16 + rl) * 128 + kk * 64 + kb);
        acc[mi] = __builtin_amdgcn_mfma_f32_16x16x32_bf16(af, bfr, acc[mi], 0, 0, 0);
      }
    }
    __syncthreads();
    cur ^= 1;
  }
  int o = w * 16 + rl;
#pragma unroll
  for (int mi = 0; mi < 2; ++mi)
#pragma unroll
    for (int i = 0; i < 4; ++i) {
      int m = brow + mi * 16 + (l >> 4) * 4 + i;
      float v = acc[mi][i];
      const float* ar = attn + (size_t)m * 16;
#pragma unroll
      for (int e2 = 0; e2 < 16; ++e2) v = fmaf(ar[e2], b2[e2 * 64 + o], v);
      out[(size_t)m * 64 + o] = v;
    }
}

// ---------------- launch -----------------------------------------------------
extern "C" void kernel_launch(void* const* d_in, const int* in_sizes, int n_in,
                              void* d_out, int out_size, void* d_ws, size_t ws_size,
                              hipStream_t stream) {
  (void)in_sizes; (void)n_in; (void)out_size; (void)ws_size;
  const float* z  = (const float*)d_in[0];
  const float* W1 = (const float*)d_in[1];
  const float* b1 = (const float*)d_in[2];
  const float* W2 = (const float*)d_in[3];
  const float* b2 = (const float*)d_in[4];
  const float* Wa = (const float*)d_in[5];
  const float* ba = (const float*)d_in[6];
  float* out = (float*)d_out;
  char* ws = (char*)d_ws;
  u16*   W1T  = (u16*)(ws);                     // 8 MB
  u16*   W2T  = (u16*)(ws + 8388608);           // 256 KB
  u16*   WaB  = (u16*)(ws + 8650752);           // 64 KB
  u16*   zb   = (u16*)(ws + 8716288);           // 32 MB
  float* attn = (float*)(ws + 42270720);        // 512 KB
  u16*   H    = (u16*)(ws + 42795008);          // 32 MB

  (void)hipFuncSetAttribute((const void*)k_gemm1,
                            hipFuncAttributeMaxDynamicSharedMemorySize, 131072);

  k_prep_w1 <<<2048, 256, 0, stream>>>(W1, W1T);
  k_prep_w2 <<<64,   256, 0, stream>>>(W2, W2T);
  k_prep_wa <<<16,   256, 0, stream>>>(Wa, WaB);
  k_attn_cast<<<1024, 256, 0, stream>>>(z, WaB, ba, zb, attn);
  k_gemm1   <<<256,  512, 131072, stream>>>(zb, W1T, b1, attn, H);
  k_gemm2   <<<256,  256, 0, stream>>>(H, W2T, attn, b2, out);
}